// Round 1
// baseline (860.406 us; speedup 1.0000x reference)
//
#include <hip/hip_runtime.h>
#include <hip/hip_bf16.h>
#include <cstdint>
#include <cstddef>

// ---- problem constants (DeepSeek-V3 MoE config) ----
#define T_TOK 1024
#define H_DIM 1024
#define I_DIM 704
#define E_NUM 64
#define TOPK 8
#define NGRP 8
#define GSIZE 8          // E_NUM / NGRP
#define TOPKG 4
#define SI_DIM 1408
#define RSCALE 2.5f
#define NSLOT (T_TOK * TOPK)   // 8192

#define AP 72            // LDS row pitch in bf16 elems

typedef short bf16x8 __attribute__((ext_vector_type(8)));
typedef float f32x4 __attribute__((ext_vector_type(4)));

__device__ inline unsigned pk2(float x, float y) {
    __hip_bfloat162 h2 = __float22bfloat162_rn(make_float2(x, y));
    unsigned u; __builtin_memcpy(&u, &h2, 4); return u;
}
__device__ inline unsigned short bf1(float x) {
    __hip_bfloat16 h = __float2bfloat16(x);
    unsigned short u; __builtin_memcpy(&u, &h, 2); return u;
}

// ---------------- routing ----------------
__global__ __launch_bounds__(64) void route_kernel(
    const float* __restrict__ x, const float* __restrict__ gw, const float* __restrict__ gb,
    int* __restrict__ counts, int* __restrict__ tk_idx, float* __restrict__ tk_w)
{
    const int t = blockIdx.x;
    __shared__ float xs[H_DIM];
    __shared__ float raw[E_NUM];
    __shared__ float sc[E_NUM];
    __shared__ float masked[E_NUM];
    __shared__ float gsc[NGRP];
    const int tid = threadIdx.x;

    const float4* xrow = (const float4*)(x + (size_t)t * H_DIM);
    for (int i = tid; i < H_DIM / 4; i += 64) ((float4*)xs)[i] = xrow[i];
    __syncthreads();

    float a = 0.f;
    const float* w = gw + (size_t)tid * H_DIM;
    for (int h = 0; h < H_DIM; h += 4) {
        float4 w4 = *(const float4*)(w + h);
        a += xs[h] * w4.x + xs[h+1] * w4.y + xs[h+2] * w4.z + xs[h+3] * w4.w;
    }
    float s = 1.f / (1.f + expf(-a));
    raw[tid] = s;
    sc[tid] = s + gb[tid];
    __syncthreads();

    if (tid == 0) {
        for (int g = 0; g < NGRP; ++g) {
            float m1 = -1e30f, m2 = -1e30f;
            for (int j = 0; j < GSIZE; ++j) {
                float v = sc[g * GSIZE + j];
                if (v > m1) { m2 = m1; m1 = v; }
                else if (v > m2) { m2 = v; }
            }
            gsc[g] = m1 + m2;
        }
        bool gsel[NGRP];
        for (int g = 0; g < NGRP; ++g) gsel[g] = false;
        for (int k = 0; k < TOPKG; ++k) {
            int best = -1; float bv = -1e30f;
            for (int g = 0; g < NGRP; ++g)
                if (!gsel[g] && gsc[g] > bv) { bv = gsc[g]; best = g; }
            gsel[best] = true;
        }
        for (int e = 0; e < E_NUM; ++e)
            masked[e] = gsel[e / GSIZE] ? sc[e] : 0.0f;
        int idx[TOPK];
        float wsum = 0.f;
        for (int k = 0; k < TOPK; ++k) {
            int best = 0; float bv = -1e30f;
            for (int e = 0; e < E_NUM; ++e)
                if (masked[e] > bv) { bv = masked[e]; best = e; }
            masked[best] = -1e30f;
            idx[k] = best;
            wsum += raw[best];
        }
        float inv = RSCALE / (wsum + 1e-20f);
        for (int k = 0; k < TOPK; ++k) {
            tk_idx[t * TOPK + k] = idx[k];
            tk_w[t * TOPK + k] = raw[idx[k]] * inv;
            atomicAdd(&counts[idx[k]], 1);
        }
    }
}

__global__ void zero_kernel(int* counts, int* fillc)
{
    int i = threadIdx.x;
    if (i < E_NUM) { counts[i] = 0; fillc[i] = 0; }
}

__global__ void scan_kernel(const int* __restrict__ counts, int* __restrict__ offs)
{
    if (threadIdx.x == 0) {
        int acc = 0;
        for (int e = 0; e < E_NUM; ++e) { offs[e] = acc; acc += counts[e]; }
    }
}

__global__ void fill_kernel(const int* __restrict__ tk_idx, const float* __restrict__ tk_w,
                            const int* __restrict__ offs, int* __restrict__ fillc,
                            int* __restrict__ tok_list, float* __restrict__ w_list,
                            int* __restrict__ tk_pos)
{
    int t = blockIdx.x * blockDim.x + threadIdx.x;
    if (t >= T_TOK) return;
    for (int k = 0; k < TOPK; ++k) {
        int e = tk_idx[t * TOPK + k];
        int pos = offs[e] + atomicAdd(&fillc[e], 1);
        tok_list[pos] = t;
        w_list[pos] = tk_w[t * TOPK + k];
        tk_pos[t * TOPK + k] = pos;
    }
}

// ---------------- routed gate/up: MFMA, register-prefetch pipelined ----------------
__global__ __launch_bounds__(256) void gateup_routed_mfma(
    const float* __restrict__ x, const float* __restrict__ Wg, const float* __restrict__ Wu,
    const int* __restrict__ offs, const int* __restrict__ counts,
    const int* __restrict__ tok_list, const float* __restrict__ w_list,
    unsigned short* __restrict__ act)
{
    const int e = blockIdx.z;
    const int cnt = counts[e];
    const int m0 = blockIdx.y * 128;
    if (m0 >= cnt) return;
    const int off = offs[e];
    const int n0 = blockIdx.x * 64;

    __shared__ unsigned short As[128 * AP];
    __shared__ unsigned short Bg[64 * AP];
    __shared__ unsigned short Bu[64 * AP];
    __shared__ int toks[128];
    __shared__ float wts[128];

    const int tid = threadIdx.x;
    if (tid < 128) {
        int s = m0 + tid;
        // clamp to token 0 for pad rows: values are garbage but finite, and the
        // corresponding C rows are masked at the epilogue (row->row mapping in MFMA)
        toks[tid] = (s < cnt) ? tok_list[off + s] : 0;
        wts[tid]  = (s < cnt) ? w_list[off + s] : 0.f;
    }
    __syncthreads();

    const int lane = tid & 63;
    const int wv = tid >> 6;
    const int lr = lane & 15;
    const int lq = lane >> 4;
    const int ar = tid >> 4;          // 0..15
    const int ac = (tid & 15) * 4;    // 0..60

    const float* ax[8];
    #pragma unroll
    for (int p = 0; p < 8; ++p)
        ax[p] = x + (size_t)toks[ar + p * 16] * H_DIM + ac;
    const float* wgp = Wg + (size_t)e * I_DIM * H_DIM + (size_t)(n0 + ar) * H_DIM + ac;
    const float* wup = Wu + (size_t)e * I_DIM * H_DIM + (size_t)(n0 + ar) * H_DIM + ac;

    f32x4 accg[2][4], accu[2][4];
    #pragma unroll
    for (int i = 0; i < 2; ++i)
        #pragma unroll
        for (int j = 0; j < 4; ++j) {
            accg[i][j] = (f32x4){0.f, 0.f, 0.f, 0.f};
            accu[i][j] = (f32x4){0.f, 0.f, 0.f, 0.f};
        }

    float4 pa[8], pbg[4], pbu[4];

    // prologue: load k0 = 0 into regs, convert to LDS
    #pragma unroll
    for (int p = 0; p < 8; ++p) pa[p] = *(const float4*)(ax[p]);
    #pragma unroll
    for (int p = 0; p < 4; ++p) {
        pbg[p] = *(const float4*)(wgp + (size_t)p * 16 * H_DIM);
        pbu[p] = *(const float4*)(wup + (size_t)p * 16 * H_DIM);
    }
    #pragma unroll
    for (int p = 0; p < 8; ++p)
        *(uint2*)&As[(ar + p * 16) * AP + ac] = make_uint2(pk2(pa[p].x, pa[p].y), pk2(pa[p].z, pa[p].w));
    #pragma unroll
    for (int p = 0; p < 4; ++p) {
        *(uint2*)&Bg[(ar + p * 16) * AP + ac] = make_uint2(pk2(pbg[p].x, pbg[p].y), pk2(pbg[p].z, pbg[p].w));
        *(uint2*)&Bu[(ar + p * 16) * AP + ac] = make_uint2(pk2(pbu[p].x, pbu[p].y), pk2(pbu[p].z, pbu[p].w));
    }
    __syncthreads();

    for (int k0 = 0; k0 < H_DIM; k0 += 64) {
        const int kn = k0 + 64;
        // issue next tile's global loads BEFORE the MFMA cluster (latency hides under MFMA+barrier)
        if (kn < H_DIM) {
            #pragma unroll
            for (int p = 0; p < 8; ++p) pa[p] = *(const float4*)(ax[p] + kn);
            #pragma unroll
            for (int p = 0; p < 4; ++p) {
                pbg[p] = *(const float4*)(wgp + (size_t)p * 16 * H_DIM + kn);
                pbu[p] = *(const float4*)(wup + (size_t)p * 16 * H_DIM + kn);
            }
        }
        #pragma unroll
        for (int ks = 0; ks < 2; ++ks) {
            bf16x8 a0 = *(const bf16x8*)&As[(wv * 32 + lr) * AP + ks * 32 + lq * 8];
            bf16x8 a1 = *(const bf16x8*)&As[(wv * 32 + 16 + lr) * AP + ks * 32 + lq * 8];
            #pragma unroll
            for (int nj = 0; nj < 4; ++nj) {
                bf16x8 bg = *(const bf16x8*)&Bg[(nj * 16 + lr) * AP + ks * 32 + lq * 8];
                bf16x8 bu = *(const bf16x8*)&Bu[(nj * 16 + lr) * AP + ks * 32 + lq * 8];
                accg[0][nj] = __builtin_amdgcn_mfma_f32_16x16x32_bf16(a0, bg, accg[0][nj], 0, 0, 0);
                accg[1][nj] = __builtin_amdgcn_mfma_f32_16x16x32_bf16(a1, bg, accg[1][nj], 0, 0, 0);
                accu[0][nj] = __builtin_amdgcn_mfma_f32_16x16x32_bf16(a0, bu, accu[0][nj], 0, 0, 0);
                accu[1][nj] = __builtin_amdgcn_mfma_f32_16x16x32_bf16(a1, bu, accu[1][nj], 0, 0, 0);
            }
        }
        if (kn >= H_DIM) break;
        __syncthreads();
        #pragma unroll
        for (int p = 0; p < 8; ++p)
            *(uint2*)&As[(ar + p * 16) * AP + ac] = make_uint2(pk2(pa[p].x, pa[p].y), pk2(pa[p].z, pa[p].w));
        #pragma unroll
        for (int p = 0; p < 4; ++p) {
            *(uint2*)&Bg[(ar + p * 16) * AP + ac] = make_uint2(pk2(pbg[p].x, pbg[p].y), pk2(pbg[p].z, pbg[p].w));
            *(uint2*)&Bu[(ar + p * 16) * AP + ac] = make_uint2(pk2(pbu[p].x, pbu[p].y), pk2(pbu[p].z, pbu[p].w));
        }
        __syncthreads();
    }

    #pragma unroll
    for (int mi = 0; mi < 2; ++mi) {
        #pragma unroll
        for (int r = 0; r < 4; ++r) {
            int srow = wv * 32 + mi * 16 + lq * 4 + r;
            if (m0 + srow < cnt) {
                float w = wts[srow];
                unsigned short* ap = act + (size_t)(off + m0 + srow) * I_DIM + n0 + lr;
                #pragma unroll
                for (int nj = 0; nj < 4; ++nj) {
                    float g = accg[mi][nj][r];
                    float u = accu[mi][nj][r];
                    float a = w * (g / (1.f + __expf(-g))) * u;
                    ap[nj * 16] = bf1(a);
                }
            }
        }
    }
}

// ---------------- routed down proj: MFMA pipelined, per-slot output (no atomics) ----------------
__global__ __launch_bounds__(256) void down_routed_mfma(
    const unsigned short* __restrict__ act, const float* __restrict__ Wd,
    const int* __restrict__ offs, const int* __restrict__ counts,
    float* __restrict__ slot_out)
{
    const int e = blockIdx.z;
    const int cnt = counts[e];
    const int m0 = blockIdx.y * 128;
    if (m0 >= cnt) return;
    const int off = offs[e];
    const int n0 = blockIdx.x * 64;

    __shared__ unsigned short As[128 * AP];
    __shared__ unsigned short Bs[64 * AP];

    const int tid = threadIdx.x;
    const int lane = tid & 63;
    const int wv = tid >> 6;
    const int lr = lane & 15;
    const int lq = lane >> 4;
    const int ar = tid >> 4;
    const int ac = (tid & 15) * 4;

    const unsigned short* ap8[8];
    #pragma unroll
    for (int p = 0; p < 8; ++p) {
        int r = m0 + ar + p * 16;
        if (r > cnt - 1) r = cnt - 1;   // clamp: pad rows re-read a valid row, masked at store
        ap8[p] = act + (size_t)(off + r) * I_DIM + ac;
    }
    const float* wdp = Wd + (size_t)e * H_DIM * I_DIM + (size_t)(n0 + ar) * I_DIM + ac;

    f32x4 acc[2][4];
    #pragma unroll
    for (int i = 0; i < 2; ++i)
        #pragma unroll
        for (int j = 0; j < 4; ++j)
            acc[i][j] = (f32x4){0.f, 0.f, 0.f, 0.f};

    uint2 pa[8]; float4 pb[4];

    #pragma unroll
    for (int p = 0; p < 8; ++p) pa[p] = *(const uint2*)(ap8[p]);
    #pragma unroll
    for (int p = 0; p < 4; ++p) pb[p] = *(const float4*)(wdp + (size_t)p * 16 * I_DIM);
    #pragma unroll
    for (int p = 0; p < 8; ++p) *(uint2*)&As[(ar + p * 16) * AP + ac] = pa[p];
    #pragma unroll
    for (int p = 0; p < 4; ++p)
        *(uint2*)&Bs[(ar + p * 16) * AP + ac] = make_uint2(pk2(pb[p].x, pb[p].y), pk2(pb[p].z, pb[p].w));
    __syncthreads();

    for (int k0 = 0; k0 < I_DIM; k0 += 64) {
        const int kn = k0 + 64;
        if (kn < I_DIM) {
            #pragma unroll
            for (int p = 0; p < 8; ++p) pa[p] = *(const uint2*)(ap8[p] + kn);
            #pragma unroll
            for (int p = 0; p < 4; ++p) pb[p] = *(const float4*)(wdp + (size_t)p * 16 * I_DIM + kn);
        }
        #pragma unroll
        for (int ks = 0; ks < 2; ++ks) {
            bf16x8 a0 = *(const bf16x8*)&As[(wv * 32 + lr) * AP + ks * 32 + lq * 8];
            bf16x8 a1 = *(const bf16x8*)&As[(wv * 32 + 16 + lr) * AP + ks * 32 + lq * 8];
            #pragma unroll
            for (int nj = 0; nj < 4; ++nj) {
                bf16x8 b = *(const bf16x8*)&Bs[(nj * 16 + lr) * AP + ks * 32 + lq * 8];
                acc[0][nj] = __builtin_amdgcn_mfma_f32_16x16x32_bf16(a0, b, acc[0][nj], 0, 0, 0);
                acc[1][nj] = __builtin_amdgcn_mfma_f32_16x16x32_bf16(a1, b, acc[1][nj], 0, 0, 0);
            }
        }
        if (kn >= I_DIM) break;
        __syncthreads();
        #pragma unroll
        for (int p = 0; p < 8; ++p) *(uint2*)&As[(ar + p * 16) * AP + ac] = pa[p];
        #pragma unroll
        for (int p = 0; p < 4; ++p)
            *(uint2*)&Bs[(ar + p * 16) * AP + ac] = make_uint2(pk2(pb[p].x, pb[p].y), pk2(pb[p].z, pb[p].w));
        __syncthreads();
    }

    #pragma unroll
    for (int mi = 0; mi < 2; ++mi) {
        #pragma unroll
        for (int r = 0; r < 4; ++r) {
            int srow = wv * 32 + mi * 16 + lq * 4 + r;
            if (m0 + srow < cnt) {
                float* op = slot_out + (size_t)(off + m0 + srow) * H_DIM + n0 + lr;
                #pragma unroll
                for (int nj = 0; nj < 4; ++nj)
                    op[nj * 16] = acc[mi][nj][r];
            }
        }
    }
}

// ---------------- combine: out[t] += sum_k slot_out[pos(t,k)] ----------------
__global__ __launch_bounds__(256) void combine_kernel(
    const float* __restrict__ slot_out, const int* __restrict__ tk_pos,
    float* __restrict__ out)
{
    const int t = blockIdx.x;
    __shared__ int pos[TOPK];
    if (threadIdx.x < TOPK) pos[threadIdx.x] = tk_pos[t * TOPK + threadIdx.x];
    __syncthreads();
    const int i = threadIdx.x;   // 256 threads x float4 = 1024 floats
    float4 a = ((const float4*)(out + (size_t)t * H_DIM))[i];
    #pragma unroll
    for (int k = 0; k < TOPK; ++k) {
        float4 v = ((const float4*)(slot_out + (size_t)pos[k] * H_DIM))[i];
        a.x += v.x; a.y += v.y; a.z += v.z; a.w += v.w;
    }
    ((float4*)(out + (size_t)t * H_DIM))[i] = a;
}

// ---------------- shared expert gate/up: MFMA dense, pipelined ----------------
__global__ __launch_bounds__(256) void gateup_shared_mfma(
    const float* __restrict__ x, const float* __restrict__ Sg, const float* __restrict__ Su,
    unsigned short* __restrict__ sact)
{
    const int m0 = blockIdx.y * 128;
    const int n0 = blockIdx.x * 64;

    __shared__ unsigned short As[128 * AP];
    __shared__ unsigned short Bg[64 * AP];
    __shared__ unsigned short Bu[64 * AP];

    const int tid = threadIdx.x;
    const int lane = tid & 63;
    const int wv = tid >> 6;
    const int lr = lane & 15;
    const int lq = lane >> 4;
    const int ar = tid >> 4;
    const int ac = (tid & 15) * 4;

    const float* xp = x + (size_t)(m0 + ar) * H_DIM + ac;
    const float* gp = Sg + (size_t)(n0 + ar) * H_DIM + ac;
    const float* up = Su + (size_t)(n0 + ar) * H_DIM + ac;

    f32x4 accg[2][4], accu[2][4];
    #pragma unroll
    for (int i = 0; i < 2; ++i)
        #pragma unroll
        for (int j = 0; j < 4; ++j) {
            accg[i][j] = (f32x4){0.f, 0.f, 0.f, 0.f};
            accu[i][j] = (f32x4){0.f, 0.f, 0.f, 0.f};
        }

    float4 pa[8], pbg[4], pbu[4];

    #pragma unroll
    for (int p = 0; p < 8; ++p) pa[p] = *(const float4*)(xp + (size_t)p * 16 * H_DIM);
    #pragma unroll
    for (int p = 0; p < 4; ++p) {
        pbg[p] = *(const float4*)(gp + (size_t)p * 16 * H_DIM);
        pbu[p] = *(const float4*)(up + (size_t)p * 16 * H_DIM);
    }
    #pragma unroll
    for (int p = 0; p < 8; ++p)
        *(uint2*)&As[(ar + p * 16) * AP + ac] = make_uint2(pk2(pa[p].x, pa[p].y), pk2(pa[p].z, pa[p].w));
    #pragma unroll
    for (int p = 0; p < 4; ++p) {
        *(uint2*)&Bg[(ar + p * 16) * AP + ac] = make_uint2(pk2(pbg[p].x, pbg[p].y), pk2(pbg[p].z, pbg[p].w));
        *(uint2*)&Bu[(ar + p * 16) * AP + ac] = make_uint2(pk2(pbu[p].x, pbu[p].y), pk2(pbu[p].z, pbu[p].w));
    }
    __syncthreads();

    for (int k0 = 0; k0 < H_DIM; k0 += 64) {
        const int kn = k0 + 64;
        if (kn < H_DIM) {
            #pragma unroll
            for (int p = 0; p < 8; ++p) pa[p] = *(const float4*)(xp + (size_t)p * 16 * H_DIM + kn);
            #pragma unroll
            for (int p = 0; p < 4; ++p) {
                pbg[p] = *(const float4*)(gp + (size_t)p * 16 * H_DIM + kn);
                pbu[p] = *(const float4*)(up + (size_t)p * 16 * H_DIM + kn);
            }
        }
        #pragma unroll
        for (int ks = 0; ks < 2; ++ks) {
            bf16x8 a0 = *(const bf16x8*)&As[(wv * 32 + lr) * AP + ks * 32 + lq * 8];
            bf16x8 a1 = *(const bf16x8*)&As[(wv * 32 + 16 + lr) * AP + ks * 32 + lq * 8];
            #pragma unroll
            for (int nj = 0; nj < 4; ++nj) {
                bf16x8 bg = *(const bf16x8*)&Bg[(nj * 16 + lr) * AP + ks * 32 + lq * 8];
                bf16x8 bu = *(const bf16x8*)&Bu[(nj * 16 + lr) * AP + ks * 32 + lq * 8];
                accg[0][nj] = __builtin_amdgcn_mfma_f32_16x16x32_bf16(a0, bg, accg[0][nj], 0, 0, 0);
                accg[1][nj] = __builtin_amdgcn_mfma_f32_16x16x32_bf16(a1, bg, accg[1][nj], 0, 0, 0);
                accu[0][nj] = __builtin_amdgcn_mfma_f32_16x16x32_bf16(a0, bu, accu[0][nj], 0, 0, 0);
                accu[1][nj] = __builtin_amdgcn_mfma_f32_16x16x32_bf16(a1, bu, accu[1][nj], 0, 0, 0);
            }
        }
        if (kn >= H_DIM) break;
        __syncthreads();
        #pragma unroll
        for (int p = 0; p < 8; ++p)
            *(uint2*)&As[(ar + p * 16) * AP + ac] = make_uint2(pk2(pa[p].x, pa[p].y), pk2(pa[p].z, pa[p].w));
        #pragma unroll
        for (int p = 0; p < 4; ++p) {
            *(uint2*)&Bg[(ar + p * 16) * AP + ac] = make_uint2(pk2(pbg[p].x, pbg[p].y), pk2(pbg[p].z, pbg[p].w));
            *(uint2*)&Bu[(ar + p * 16) * AP + ac] = make_uint2(pk2(pbu[p].x, pbu[p].y), pk2(pbu[p].z, pbu[p].w));
        }
        __syncthreads();
    }

    #pragma unroll
    for (int mi = 0; mi < 2; ++mi) {
        #pragma unroll
        for (int r = 0; r < 4; ++r) {
            int trow = m0 + wv * 32 + mi * 16 + lq * 4 + r;
            unsigned short* sp = sact + (size_t)trow * SI_DIM + n0 + lr;
            #pragma unroll
            for (int nj = 0; nj < 4; ++nj) {
                float g = accg[mi][nj][r];
                float u = accu[mi][nj][r];
                float a = (g / (1.f + __expf(-g))) * u;
                sp[nj * 16] = bf1(a);
            }
        }
    }
}

// ---------------- shared expert down proj: MFMA dense, pipelined ----------------
__global__ __launch_bounds__(256) void down_shared_mfma(
    const unsigned short* __restrict__ sact, const float* __restrict__ Sd,
    float* __restrict__ out)
{
    const int m0 = blockIdx.y * 128;
    const int n0 = blockIdx.x * 64;

    __shared__ unsigned short As[128 * AP];
    __shared__ unsigned short Bs[64 * AP];

    const int tid = threadIdx.x;
    const int lane = tid & 63;
    const int wv = tid >> 6;
    const int lr = lane & 15;
    const int lq = lane >> 4;
    const int ar = tid >> 4;
    const int ac = (tid & 15) * 4;

    const unsigned short* sp = sact + (size_t)(m0 + ar) * SI_DIM + ac;
    const float* wp = Sd + (size_t)(n0 + ar) * SI_DIM + ac;

    f32x4 acc[2][4];
    #pragma unroll
    for (int i = 0; i < 2; ++i)
        #pragma unroll
        for (int j = 0; j < 4; ++j)
            acc[i][j] = (f32x4){0.f, 0.f, 0.f, 0.f};

    uint2 pa[8]; float4 pb[4];

    #pragma unroll
    for (int p = 0; p < 8; ++p) pa[p] = *(const uint2*)(sp + (size_t)p * 16 * SI_DIM);
    #pragma unroll
    for (int p = 0; p < 4; ++p) pb[p] = *(const float4*)(wp + (size_t)p * 16 * SI_DIM);
    #pragma unroll
    for (int p = 0; p < 8; ++p) *(uint2*)&As[(ar + p * 16) * AP + ac] = pa[p];
    #pragma unroll
    for (int p = 0; p < 4; ++p)
        *(uint2*)&Bs[(ar + p * 16) * AP + ac] = make_uint2(pk2(pb[p].x, pb[p].y), pk2(pb[p].z, pb[p].w));
    __syncthreads();

    for (int k0 = 0; k0 < SI_DIM; k0 += 64) {
        const int kn = k0 + 64;
        if (kn < SI_DIM) {
            #pragma unroll
            for (int p = 0; p < 8; ++p) pa[p] = *(const uint2*)(sp + (size_t)p * 16 * SI_DIM + kn);
            #pragma unroll
            for (int p = 0; p < 4; ++p) pb[p] = *(const float4*)(wp + (size_t)p * 16 * SI_DIM + kn);
        }
        #pragma unroll
        for (int ks = 0; ks < 2; ++ks) {
            bf16x8 a0 = *(const bf16x8*)&As[(wv * 32 + lr) * AP + ks * 32 + lq * 8];
            bf16x8 a1 = *(const bf16x8*)&As[(wv * 32 + 16 + lr) * AP + ks * 32 + lq * 8];
            #pragma unroll
            for (int nj = 0; nj < 4; ++nj) {
                bf16x8 b = *(const bf16x8*)&Bs[(nj * 16 + lr) * AP + ks * 32 + lq * 8];
                acc[0][nj] = __builtin_amdgcn_mfma_f32_16x16x32_bf16(a0, b, acc[0][nj], 0, 0, 0);
                acc[1][nj] = __builtin_amdgcn_mfma_f32_16x16x32_bf16(a1, b, acc[1][nj], 0, 0, 0);
            }
        }
        if (kn >= SI_DIM) break;
        __syncthreads();
        #pragma unroll
        for (int p = 0; p < 8; ++p) *(uint2*)&As[(ar + p * 16) * AP + ac] = pa[p];
        #pragma unroll
        for (int p = 0; p < 4; ++p)
            *(uint2*)&Bs[(ar + p * 16) * AP + ac] = make_uint2(pk2(pb[p].x, pb[p].y), pk2(pb[p].z, pb[p].w));
        __syncthreads();
    }

    #pragma unroll
    for (int mi = 0; mi < 2; ++mi) {
        #pragma unroll
        for (int r = 0; r < 4; ++r) {
            int trow = m0 + wv * 32 + mi * 16 + lq * 4 + r;
            float* op = out + (size_t)trow * H_DIM + n0 + lr;
            #pragma unroll
            for (int nj = 0; nj < 4; ++nj)
                op[nj * 16] = acc[mi][nj][r];
        }
    }
}

// ---------------- launch ----------------
extern "C" void kernel_launch(void* const* d_in, const int* in_sizes, int n_in,
                              void* d_out, int out_size, void* d_ws, size_t ws_size,
                              hipStream_t stream)
{
    const float* x  = (const float*)d_in[0];
    const float* gw = (const float*)d_in[1];
    const float* gb = (const float*)d_in[2];
    const float* Wg = (const float*)d_in[3];
    const float* Wu = (const float*)d_in[4];
    const float* Wd = (const float*)d_in[5];
    const float* Sg = (const float*)d_in[6];
    const float* Su = (const float*)d_in[7];
    const float* Sd = (const float*)d_in[8];
    float* out = (float*)d_out;

    // workspace layout (16B-aligned chunks first)
    float* slot_out = (float*)d_ws;                                   // 8192*1024 f32  (33.5 MB)
    unsigned short* act  = (unsigned short*)(slot_out + (size_t)NSLOT * H_DIM);  // 8192*704 bf16
    unsigned short* sact = act + (size_t)NSLOT * I_DIM;               // 1024*1408 bf16
    int* counts   = (int*)(sact + (size_t)T_TOK * SI_DIM);            // 64
    int* fillc    = counts + 64;                                      // 64
    int* offs     = fillc + 64;                                       // 64
    int* tk_idx   = offs + 64;                                        // 8192
    float* tk_w   = (float*)(tk_idx + NSLOT);                         // 8192
    int* tok_list = (int*)(tk_w + NSLOT);                             // 8192
    float* w_list = (float*)(tok_list + NSLOT);                       // 8192
    int* tk_pos   = (int*)(w_list + NSLOT);                           // 8192

    zero_kernel<<<1, 64, 0, stream>>>(counts, fillc);
    route_kernel<<<T_TOK, 64, 0, stream>>>(x, gw, gb, counts, tk_idx, tk_w);
    scan_kernel<<<1, 64, 0, stream>>>(counts, offs);
    fill_kernel<<<4, 256, 0, stream>>>(tk_idx, tk_w, offs, fillc, tok_list, w_list, tk_pos);

    gateup_routed_mfma<<<dim3(11, 8, 64), 256, 0, stream>>>(x, Wg, Wu, offs, counts, tok_list, w_list, act);
    gateup_shared_mfma<<<dim3(22, 8, 1), 256, 0, stream>>>(x, Sg, Su, sact);
    down_shared_mfma<<<dim3(16, 8, 1), 256, 0, stream>>>(sact, Sd, out);
    down_routed_mfma<<<dim3(16, 8, 64), 256, 0, stream>>>(act, Wd, offs, counts, slot_out);
    combine_kernel<<<T_TOK, 256, 0, stream>>>(slot_out, tk_pos, out);
}